// Round 7
// baseline (1530.145 us; speedup 1.0000x reference)
//
#include <hip/hip_runtime.h>
#include <hip/hip_bf16.h>
#include <math.h>

// Problem constants: S=512, B=256, V=100000, E=128, H=256
#define S_LEN 512
#define B_SZ  256
#define E_SZ  128
#define H_SZ  256
#define HPAD  264   // LDS state-row stride in shorts (16B-aligned)

typedef __attribute__((ext_vector_type(8))) short bf16x8;
typedef __attribute__((ext_vector_type(4))) float f32x4;

__device__ __forceinline__ short f2bf(float f) {
    union { float f; unsigned u; } v; v.f = f;
    unsigned r = v.u + 0x7FFFu + ((v.u >> 16) & 1u);   // RNE
    return (short)(r >> 16);
}
__device__ __forceinline__ float bf2f(unsigned short u) {
    union { unsigned u; float f; } v; v.u = ((unsigned)u) << 16; return v.f;
}
__device__ __forceinline__ unsigned pk2bf(float a, float b) {
    union { __hip_bfloat162 h; unsigned u; } v;
    v.h = __float22bfloat162_rn(make_float2(a, b));     // v_cvt_pk_bf16_f32
    return v.u;
}
__device__ __forceinline__ float tanh_fast(float v) {
    return 1.f - 2.f / (__expf(2.f * v) + 1.f);         // exact at +/-inf
}

// ---------------------------------------------------------------------------
// Kernel 1: embedding gather + input projection via MFMA.
// Output TRANSPOSED: xproj[b][s][h] bf16 — scan lanes then stream their row.
// ---------------------------------------------------------------------------
#define PROJ_RPB 128
__global__ __launch_bounds__(256) void proj_kernel(
    const int*   __restrict__ X,
    const float* __restrict__ emb,
    const float* __restrict__ W_ih,
    const float* __restrict__ b_ih,
    const float* __restrict__ b_hh,
    unsigned short* __restrict__ xproj)
{
    const int tid  = threadIdx.x;
    const int wave = tid >> 6;
    const int lane = tid & 63;
    const int bl   = lane & 15;
    const int quad = lane >> 4;

    __shared__ short slab[16][HPAD];

    bf16x8 wfrag[4][4];
    float4 bias[4];
#pragma unroll
    for (int mt = 0; mt < 4; ++mt) {
        const int tile = wave * 4 + mt;
        const int hA   = tile * 16 + bl;
#pragma unroll
        for (int kk = 0; kk < 4; ++kk) {
            const float* p = W_ih + (size_t)hA * E_SZ + kk * 32 + quad * 8;
            float4 a = *(const float4*)p, b = *(const float4*)(p + 4);
            bf16x8 f;
            f[0]=f2bf(a.x); f[1]=f2bf(a.y); f[2]=f2bf(a.z); f[3]=f2bf(a.w);
            f[4]=f2bf(b.x); f[5]=f2bf(b.y); f[6]=f2bf(b.z); f[7]=f2bf(b.w);
            wfrag[mt][kk] = f;
        }
        const int hb = tile * 16 + quad * 4;
        float4 bi = *(const float4*)(b_ih + hb);
        float4 bh = *(const float4*)(b_hh + hb);
        bias[mt] = make_float4(bi.x + bh.x, bi.y + bh.y, bi.z + bh.z, bi.w + bh.w);
    }

    const int row0 = blockIdx.x * PROJ_RPB;
#pragma unroll
    for (int rg = 0; rg < PROJ_RPB / 16; ++rg) {
        const int r0  = row0 + rg * 16;
        const int tok = X[r0 + bl];

        bf16x8 bfr[4];
#pragma unroll
        for (int kk = 0; kk < 4; ++kk) {
            const float* p = emb + (size_t)tok * E_SZ + kk * 32 + quad * 8;
            float4 a = *(const float4*)p, b = *(const float4*)(p + 4);
            bf16x8 f;
            f[0]=f2bf(a.x); f[1]=f2bf(a.y); f[2]=f2bf(a.z); f[3]=f2bf(a.w);
            f[4]=f2bf(b.x); f[5]=f2bf(b.y); f[6]=f2bf(b.z); f[7]=f2bf(b.w);
            bfr[kk] = f;
        }
#pragma unroll
        for (int mt = 0; mt < 4; ++mt) {
            f32x4 acc = {0.f, 0.f, 0.f, 0.f};
#pragma unroll
            for (int kk = 0; kk < 4; ++kk)
                acc = __builtin_amdgcn_mfma_f32_16x16x32_bf16(wfrag[mt][kk], bfr[kk], acc, 0, 0, 0);
            const int hb = (wave * 4 + mt) * 16 + quad * 4;
            uint2 pk;
            pk.x = pk2bf(acc[0] + bias[mt].x, acc[1] + bias[mt].y);
            pk.y = pk2bf(acc[2] + bias[mt].z, acc[3] + bias[mt].w);
            *(uint2*)&slab[bl][hb] = pk;
        }
        __syncthreads();
        {
            const int row  = tid >> 4;
            const int c0   = tid & 15;
            const int flat = r0 + row;
            const int ss   = flat >> 8;
            const int bb   = flat & 255;
            unsigned short* dst = xproj + (size_t)bb * S_LEN * H_SZ + (size_t)ss * H_SZ;
#pragma unroll
            for (int j = 0; j < 2; ++j) {
                const int c16 = c0 + j * 16;
                uint4 v = *(const uint4*)&slab[row][c16 * 8];
                *(uint4*)&dst[c16 * 8] = v;
            }
        }
        __syncthreads();
    }
}

// ---------------------------------------------------------------------------
// Kernel 2: recurrent scan + log_softmax.
// 8 blocks x 32 batch rows (2 independent groups of 16). 256 threads =
// 4 waves (1/SIMD). Wave owns 4 m-tiles and computes BOTH groups: 64 MFMAs
// per step, 8 independent chains — barrier/latency amortized over 2 groups.
// W_hh in 128 VGPRs/lane; launch_bounds(256,1) so no spills (~300 VGPR).
// xp prefetch (distance 2) issued at TOP of step -> old when barrier drains.
// ---------------------------------------------------------------------------
__global__ __launch_bounds__(256, 1) void rnn_scan_kernel(
    const unsigned short* __restrict__ xproj,   // [B][S][H] bf16
    const float* __restrict__ W_hh,
    float*       __restrict__ out)
{
    const int tid  = threadIdx.x;
    const int wave = tid >> 6;
    const int lane = tid & 63;
    const int bl   = lane & 15;
    const int quad = lane >> 4;
    const int B0   = blockIdx.x * 32;

    __shared__ short Hbuf[2][32][HPAD];

    // W_hh A-fragments (shared by both groups)
    bf16x8 wfrag[4][8];
#pragma unroll
    for (int mt = 0; mt < 4; ++mt) {
        const int h = (wave * 4 + mt) * 16 + bl;
#pragma unroll
        for (int kk = 0; kk < 8; ++kk) {
            const float* wp = W_hh + (size_t)h * H_SZ + kk * 32 + quad * 8;
            float4 x0 = *(const float4*)wp, x1 = *(const float4*)(wp + 4);
            bf16x8 f;
            f[0]=f2bf(x0.x); f[1]=f2bf(x0.y); f[2]=f2bf(x0.z); f[3]=f2bf(x0.w);
            f[4]=f2bf(x1.x); f[5]=f2bf(x1.y); f[6]=f2bf(x1.z); f[7]=f2bf(x1.w);
            wfrag[mt][kk] = f;
        }
    }

    // zero initial state (buffer 0, both groups)
    for (int i = tid; i < (32 * HPAD) / 2; i += 256)
        ((unsigned*)&Hbuf[0][0][0])[i] = 0u;

    // per-lane xp stream bases for the two groups
    const unsigned short* xpb0 = xproj + (size_t)(B0 + bl) * S_LEN * H_SZ;
    const unsigned short* xpb1 = xproj + (size_t)(B0 + 16 + bl) * S_LEN * H_SZ;

    // xp ring: slot = step parity; [slot][group][mt]
    ushort4 xpr[2][2][4];
#pragma unroll
    for (int p = 0; p < 2; ++p)
#pragma unroll
        for (int mt = 0; mt < 4; ++mt) {
            const int off = (wave * 4 + mt) * 16 + quad * 4;
            xpr[p][0][mt] = *(const ushort4*)(xpb0 + (size_t)p * H_SZ + off);
            xpr[p][1][mt] = *(const ushort4*)(xpb1 + (size_t)p * H_SZ + off);
        }

    __syncthreads();

#define SCAN_STEP(P, SS)                                                       \
    do {                                                                       \
        /* state B-frags for both groups */                                    \
        bf16x8 bf0[8], bf1[8];                                                 \
        _Pragma("unroll")                                                      \
        for (int kk = 0; kk < 8; ++kk) {                                       \
            bf0[kk] = *(const bf16x8*)&Hbuf[P][bl][kk * 32 + quad * 8];        \
            bf1[kk] = *(const bf16x8*)&Hbuf[P][16 + bl][kk * 32 + quad * 8];   \
        }                                                                      \
        /* acc init from xp */                                                 \
        f32x4 a0[4], a1[4];                                                    \
        _Pragma("unroll")                                                      \
        for (int mt = 0; mt < 4; ++mt) {                                       \
            const ushort4 x0 = xpr[P][0][mt], x1 = xpr[P][1][mt];              \
            f32x4 t0 = {bf2f(x0.x), bf2f(x0.y), bf2f(x0.z), bf2f(x0.w)};       \
            f32x4 t1 = {bf2f(x1.x), bf2f(x1.y), bf2f(x1.z), bf2f(x1.w)};       \
            a0[mt] = t0; a1[mt] = t1;                                          \
        }                                                                      \
        /* early prefetch for step SS+2 (old by the time barrier drains) */    \
        if ((SS) + 2 < S_LEN) {                                                \
            _Pragma("unroll")                                                  \
            for (int mt = 0; mt < 4; ++mt) {                                   \
                const int off = (wave * 4 + mt) * 16 + quad * 4;               \
                xpr[P][0][mt] = *(const ushort4*)(xpb0 + (size_t)((SS) + 2) * H_SZ + off); \
                xpr[P][1][mt] = *(const ushort4*)(xpb1 + (size_t)((SS) + 2) * H_SZ + off); \
            }                                                                  \
        }                                                                      \
        /* 64 MFMAs: 8 independent chains of depth 8 */                        \
        _Pragma("unroll")                                                      \
        for (int kk = 0; kk < 8; ++kk)                                         \
            _Pragma("unroll")                                                  \
            for (int mt = 0; mt < 4; ++mt)                                     \
                a0[mt] = __builtin_amdgcn_mfma_f32_16x16x32_bf16(wfrag[mt][kk], bf0[kk], a0[mt], 0, 0, 0); \
        _Pragma("unroll")                                                      \
        for (int kk = 0; kk < 8; ++kk)                                         \
            _Pragma("unroll")                                                  \
            for (int mt = 0; mt < 4; ++mt)                                     \
                a1[mt] = __builtin_amdgcn_mfma_f32_16x16x32_bf16(wfrag[mt][kk], bf1[kk], a1[mt], 0, 0, 0); \
        /* epilogue: tanh + pack + LDS write, group 0 then group 1 */          \
        _Pragma("unroll")                                                      \
        for (int mt = 0; mt < 4; ++mt) {                                       \
            float t0 = tanh_fast(a0[mt][0]);                                   \
            float t1 = tanh_fast(a0[mt][1]);                                   \
            float t2 = tanh_fast(a0[mt][2]);                                   \
            float t3 = tanh_fast(a0[mt][3]);                                   \
            uint2 pk; pk.x = pk2bf(t0, t1); pk.y = pk2bf(t2, t3);              \
            *(uint2*)&Hbuf[(P) ^ 1][bl][(wave * 4 + mt) * 16 + quad * 4] = pk; \
        }                                                                      \
        _Pragma("unroll")                                                      \
        for (int mt = 0; mt < 4; ++mt) {                                       \
            float t0 = tanh_fast(a1[mt][0]);                                   \
            float t1 = tanh_fast(a1[mt][1]);                                   \
            float t2 = tanh_fast(a1[mt][2]);                                   \
            float t3 = tanh_fast(a1[mt][3]);                                   \
            uint2 pk; pk.x = pk2bf(t0, t1); pk.y = pk2bf(t2, t3);              \
            *(uint2*)&Hbuf[(P) ^ 1][16 + bl][(wave * 4 + mt) * 16 + quad * 4] = pk; \
        }                                                                      \
        __syncthreads();                                                       \
    } while (0)

    for (int s = 0; s < S_LEN; s += 2) {
        SCAN_STEP(0, s);
        SCAN_STEP(1, s + 1);
    }
#undef SCAN_STEP

    // final state in Hbuf[0] (step 511 wrote buffer 0)
    // ---- log_softmax: 2 passes; pass p: thread t -> row (t>>4)+16p,
    //      owns h in [ (t&15)*16, +16 ) ; reduce across 16 lanes ----
#pragma unroll
    for (int p = 0; p < 2; ++p) {
        const int row = (tid >> 4) + 16 * p;   // 0..31
        const int j   = tid & 15;
        float v[16];
#pragma unroll
        for (int c = 0; c < 4; ++c) {
            ushort4 hq = *(const ushort4*)&Hbuf[0][row][j * 16 + c * 4];
            v[c*4+0] = bf2f(hq.x); v[c*4+1] = bf2f(hq.y);
            v[c*4+2] = bf2f(hq.z); v[c*4+3] = bf2f(hq.w);
        }
        float m = v[0];
#pragma unroll
        for (int i = 1; i < 16; ++i) m = fmaxf(m, v[i]);
#pragma unroll
        for (int off = 1; off < 16; off <<= 1) m = fmaxf(m, __shfl_xor(m, off));
        float ss = 0.f;
#pragma unroll
        for (int i = 0; i < 16; ++i) ss += __expf(v[i] - m);
#pragma unroll
        for (int off = 1; off < 16; off <<= 1) ss += __shfl_xor(ss, off);
        const float lse = m + __logf(ss);
        float* dst = out + (size_t)(B0 + row) * H_SZ + j * 16;
#pragma unroll
        for (int c = 0; c < 4; ++c) {
            float4 o = make_float4(v[c*4+0]-lse, v[c*4+1]-lse, v[c*4+2]-lse, v[c*4+3]-lse);
            *(float4*)(dst + c * 4) = o;
        }
    }
}

// ---------------------------------------------------------------------------
extern "C" void kernel_launch(void* const* d_in, const int* in_sizes, int n_in,
                              void* d_out, int out_size, void* d_ws, size_t ws_size,
                              hipStream_t stream) {
    const int*   X    = (const int*)  d_in[0];
    const float* emb  = (const float*)d_in[1];
    const float* W_ih = (const float*)d_in[2];
    const float* W_hh = (const float*)d_in[3];
    const float* b_ih = (const float*)d_in[4];
    const float* b_hh = (const float*)d_in[5];
    float* out = (float*)d_out;

    unsigned short* xproj = (unsigned short*)d_ws;   // [B][S][H] bf16 = 67.1 MB

    proj_kernel<<<dim3(S_LEN * B_SZ / PROJ_RPB), 256, 0, stream>>>(
        X, emb, W_ih, b_ih, b_hh, xproj);

    rnn_scan_kernel<<<dim3(B_SZ / 32), 256, 0, stream>>>(xproj, W_hh, out);
}